// Round 1
// baseline (361.809 us; speedup 1.0000x reference)
//
#include <hip/hip_runtime.h>
#include <math.h>

#define BB 8
#define HH 512
#define WW 1024
#define HW (HH * WW)          // 524288 = 2^19
#define NPIX (BB * HW)        // 4194304
#define NSEG 16               // segments 1..16 (0 skipped)
#define SUPPRESS 0.1f

// ---------------- pass 1: boundary, sobel, smooth, segment moments ----------------
__global__ __launch_bounds__(256) void pass1_kernel(
    const float* __restrict__ flow,
    const int*   __restrict__ masks,
    const float* __restrict__ images,
    double* __restrict__ moments,     // [B][16][14]
    double* __restrict__ scal,        // [0]=sum_dx [1]=sum_dy [2]=Sb [3]=Sbf
    unsigned* __restrict__ maxfg_bits)
{
    __shared__ float bins[NSEG * 14];
    for (int t = threadIdx.x; t < NSEG * 14; t += 256) bins[t] = 0.f;
    __syncthreads();

    const int tid  = threadIdx.x;
    const int lane = tid & 63;
    const long long base = (long long)blockIdx.x * 4096;  // 4 rows per block
    const int b      = (int)(base >> 19);
    const int hwbase = (int)(base & (HW - 1));

    const float* fu = flow + (long long)b * (2LL * HW);
    const float* fv = fu + HW;
    const int*   mk = masks + (long long)b * HW;
    const float* i0 = images + (long long)b * (3LL * HW);
    const float* i1 = i0 + HW;
    const float* i2 = i1 + HW;

    float a_dx = 0.f, a_dy = 0.f, a_sb = 0.f, a_sbf = 0.f, mfg = 0.f;

    #pragma unroll 1
    for (int it = 0; it < 16; ++it) {
        const int hw = hwbase + it * 256 + tid;
        const int h = hw >> 10;
        const int w = hw & 1023;
        const bool topok = (h > 0), botok = (h < HH - 1);
        const bool lok = (w > 0), rok = (w < WW - 1);

        const int   segc = mk[hw];
        const float u = fu[hw], v = fv[hw];

        int   s_u = topok ? mk[hw - WW] : 0;
        int   s_d = botok ? mk[hw + WW] : 0;
        float ut = 0.f, vt = 0.f, ub = 0.f, vb = 0.f;
        if (topok) { ut = fu[hw - WW]; vt = fv[hw - WW]; }
        if (botok) { ub = fu[hw + WW]; vb = fv[hw + WW]; }

        const float m0 = sqrtf(ut * ut + vt * vt);   // 0 when !topok (zero-pad)
        const float m1 = sqrtf(u * u + v * v);
        const float m2 = sqrtf(ub * ub + vb * vb);

        const float g0 = (i0[hw] + i1[hw] + i2[hw]) * (1.f / 3.f);

        // lateral neighbors via shuffles (w % 64 == lane, rows are wave-aligned)
        float l0 = __shfl_up(m0, 1), l1 = __shfl_up(m1, 1), l2 = __shfl_up(m2, 1);
        int   slu = __shfl_up(s_u, 1), slc = __shfl_up(segc, 1), sld = __shfl_up(s_d, 1);
        float r0 = __shfl_down(m0, 1), r1 = __shfl_down(m1, 1), r2 = __shfl_down(m2, 1);
        int   sru = __shfl_down(s_u, 1), src = __shfl_down(segc, 1), srd = __shfl_down(s_d, 1);
        float ru = __shfl_down(u, 1), rv = __shfl_down(v, 1);
        float g1 = __shfl_down(g0, 1);

        if (lane == 0 && lok) {
            float a = 0.f, c = 0.f;
            if (topok) { a = fu[hw - WW - 1]; c = fv[hw - WW - 1]; }
            l0 = sqrtf(a * a + c * c);
            a = fu[hw - 1]; c = fv[hw - 1];
            l1 = sqrtf(a * a + c * c);
            a = 0.f; c = 0.f;
            if (botok) { a = fu[hw + WW - 1]; c = fv[hw + WW - 1]; }
            l2 = sqrtf(a * a + c * c);
            slu = topok ? mk[hw - WW - 1] : 0;
            slc = mk[hw - 1];
            sld = botok ? mk[hw + WW - 1] : 0;
        }
        if (lane == 63 && rok) {
            float a = 0.f, c = 0.f;
            if (topok) { a = fu[hw - WW + 1]; c = fv[hw - WW + 1]; }
            r0 = sqrtf(a * a + c * c);
            ru = fu[hw + 1]; rv = fv[hw + 1];
            r1 = sqrtf(ru * ru + rv * rv);
            a = 0.f; c = 0.f;
            if (botok) { a = fu[hw + WW + 1]; c = fv[hw + WW + 1]; }
            r2 = sqrtf(a * a + c * c);
            sru = topok ? mk[hw - WW + 1] : 0;
            src = mk[hw + 1];
            srd = botok ? mk[hw + WW + 1] : 0;
            g1 = (i0[hw + 1] + i1[hw + 1] + i2[hw + 1]) * (1.f / 3.f);
        }
        if (!lok) { l0 = l1 = l2 = 0.f; }   // zero-pad for sobel
        if (!rok) { r0 = r1 = r2 = 0.f; }

        // boundary: any in-bounds neighbor differs from center
        int bnd = 0;
        if (topok) bnd |= (s_u != segc);
        if (botok) bnd |= (s_d != segc);
        if (lok) {
            bnd |= (slc != segc);
            if (topok) bnd |= (slu != segc);
            if (botok) bnd |= (sld != segc);
        }
        if (rok) {
            bnd |= (src != segc);
            if (topok) bnd |= (sru != segc);
            if (botok) bnd |= (srd != segc);
        }

        // sobel (cross-correlation, zero padding)
        const float fgx = (r0 - l0) + 2.f * (r1 - l1) + (r2 - l2);
        const float fgy = (l2 + 2.f * m2 + r2) - (l0 + 2.f * m0 + r0);
        const float fgraw = fabsf(fgx) + fabsf(fgy);
        mfg = fmaxf(mfg, fgraw);
        if (bnd) { a_sb += 1.f; a_sbf += fgraw; }

        // boundary-aware smoothness
        if (rok) {
            const float wgt = expf(-fabsf(g1 - g0) * 10.f) * (bnd ? SUPPRESS : 1.f);
            a_dx += (fabsf(ru - u) + fabsf(rv - v)) * wgt;
        }
        if (botok) {
            const float g2 = (i0[hw + WW] + i1[hw + WW] + i2[hw + WW]) * (1.f / 3.f);
            const float wgt = expf(-fabsf(g2 - g0) * 10.f) * (bnd ? SUPPRESS : 1.f);
            a_dy += (fabsf(ub - u) + fabsf(vb - v)) * wgt;
        }

        // segment moments (skip background 0)
        if (segc != 0) {
            float* bp = &bins[(segc - 1) * 14];
            const float x = (float)w, y = (float)h;
            atomicAdd(&bp[0], 1.f);
            atomicAdd(&bp[1], x);
            atomicAdd(&bp[2], y);
            atomicAdd(&bp[3], x * x);
            atomicAdd(&bp[4], x * y);
            atomicAdd(&bp[5], y * y);
            atomicAdd(&bp[6], u);
            atomicAdd(&bp[7], v);
            atomicAdd(&bp[8], u * u);
            atomicAdd(&bp[9], v * v);
            atomicAdd(&bp[10], x * u);
            atomicAdd(&bp[11], y * u);
            atomicAdd(&bp[12], x * v);
            atomicAdd(&bp[13], y * v);
        }
    }

    // block-reduce the five scalars
    for (int off = 32; off > 0; off >>= 1) {
        a_dx += __shfl_down(a_dx, off);
        a_dy += __shfl_down(a_dy, off);
        a_sb += __shfl_down(a_sb, off);
        a_sbf += __shfl_down(a_sbf, off);
        mfg = fmaxf(mfg, __shfl_down(mfg, off));
    }
    __shared__ float wred[4][5];
    if (lane == 0) {
        const int wv = tid >> 6;
        wred[wv][0] = a_dx; wred[wv][1] = a_dy; wred[wv][2] = a_sb;
        wred[wv][3] = a_sbf; wred[wv][4] = mfg;
    }
    __syncthreads();
    if (tid == 0) {
        float dx = 0.f, dy = 0.f, sb = 0.f, sbf = 0.f, mf = 0.f;
        for (int i = 0; i < 4; ++i) {
            dx += wred[i][0]; dy += wred[i][1]; sb += wred[i][2];
            sbf += wred[i][3]; mf = fmaxf(mf, wred[i][4]);
        }
        atomicAdd(&scal[0], (double)dx);
        atomicAdd(&scal[1], (double)dy);
        atomicAdd(&scal[2], (double)sb);
        atomicAdd(&scal[3], (double)sbf);
        atomicMax(maxfg_bits, __float_as_uint(mf));  // nonneg floats: bit-monotone
    }
    if (tid < NSEG * 14)
        atomicAdd(&moments[b * (NSEG * 14) + tid], (double)bins[tid]);
}

// ---------------- solve: 3x3 normal equations + object variance ----------------
__global__ __launch_bounds__(128) void solve_kernel(
    const double* __restrict__ moments,
    float* __restrict__ params,   // [128][6]
    int* __restrict__ valid,      // [128]
    float* __restrict__ out)
{
    const int i = threadIdx.x;    // (b, seg-1)
    const double* m = &moments[i * 14];
    const double n = m[0];
    const int vh = (n >= 100.0) ? 1 : 0;
    float p[6] = {0.f, 0.f, 0.f, 0.f, 0.f, 0.f};
    if (vh) {
        double A[3][3] = {{m[3], m[4], m[1]},
                          {m[4], m[5], m[2]},
                          {m[1], m[2], n}};
        double Bm[3][2] = {{m[10], m[12]},
                           {m[11], m[13]},
                           {m[6],  m[7]}};
        for (int k = 0; k < 3; ++k) {
            int piv = k; double mx = fabs(A[k][k]);
            for (int r = k + 1; r < 3; ++r) {
                double a = fabs(A[r][k]);
                if (a > mx) { mx = a; piv = r; }
            }
            if (piv != k) {
                for (int c = 0; c < 3; ++c) { double t = A[k][c]; A[k][c] = A[piv][c]; A[piv][c] = t; }
                for (int c = 0; c < 2; ++c) { double t = Bm[k][c]; Bm[k][c] = Bm[piv][c]; Bm[piv][c] = t; }
            }
            const double inv = 1.0 / A[k][k];
            for (int r = k + 1; r < 3; ++r) {
                const double f = A[r][k] * inv;
                for (int c = k; c < 3; ++c) A[r][c] -= f * A[k][c];
                Bm[r][0] -= f * Bm[k][0];
                Bm[r][1] -= f * Bm[k][1];
            }
        }
        double X[3][2];
        for (int c = 0; c < 2; ++c) {
            X[2][c] = Bm[2][c] / A[2][2];
            X[1][c] = (Bm[1][c] - A[1][2] * X[2][c]) / A[1][1];
            X[0][c] = (Bm[0][c] - A[0][1] * X[1][c] - A[0][2] * X[2][c]) / A[0][0];
        }
        p[0] = (float)X[0][0]; p[1] = (float)X[1][0]; p[2] = (float)X[2][0];
        p[3] = (float)X[0][1]; p[4] = (float)X[1][1]; p[5] = (float)X[2][1];
    }
    valid[i] = vh;
    for (int c = 0; c < 6; ++c) params[i * 6 + c] = p[c];

    // object variance (unbiased)
    const int vv = (n >= 50.0) ? 1 : 0;
    double var = 0.0;
    if (vv) {
        const double ns = (n > 2.0) ? n : 2.0;
        const double var_u = (m[8] - m[6] * m[6] / ns) / (ns - 1.0);
        const double var_v = (m[9] - m[7] * m[7] / ns) / (ns - 1.0);
        var = var_u + var_v;
    }
    __shared__ double svar[128];
    __shared__ int scnt[128];
    svar[i] = var; scnt[i] = vv;
    __syncthreads();
    for (int s = 64; s > 0; s >>= 1) {
        if (i < s) { svar[i] += svar[i + s]; scnt[i] += scnt[i + s]; }
        __syncthreads();
    }
    if (i == 0) out[2] = (float)(svar[0] / (double)(scnt[0] > 1 ? scnt[0] : 1));
}

// ---------------- pass 2: per-pixel affine-fit residuals ----------------
__global__ __launch_bounds__(256) void pass2_kernel(
    const float* __restrict__ flow,
    const int*   __restrict__ masks,
    const float* __restrict__ params,
    const int*   __restrict__ valid,
    double* __restrict__ res_sum)
{
    __shared__ float rbins[NSEG];
    __shared__ float sp[NSEG * 6];
    __shared__ int   sv[NSEG];

    const long long base = (long long)blockIdx.x * 2048;
    const int b      = (int)(base >> 19);
    const int hwbase = (int)(base & (HW - 1));

    if (threadIdx.x < NSEG) { rbins[threadIdx.x] = 0.f; sv[threadIdx.x] = valid[b * NSEG + threadIdx.x]; }
    if (threadIdx.x < NSEG * 6) sp[threadIdx.x] = params[b * NSEG * 6 + threadIdx.x];
    __syncthreads();

    const float* fu = flow + (long long)b * (2LL * HW);
    const float* fv = fu + HW;
    const int*   mk = masks + (long long)b * HW;

    #pragma unroll 1
    for (int it = 0; it < 8; ++it) {
        const int hw = hwbase + it * 256 + threadIdx.x;
        const int segc = mk[hw];
        if (segc == 0) continue;
        if (!sv[segc - 1]) continue;
        const float* pf = &sp[(segc - 1) * 6];
        const float x = (float)(hw & 1023), y = (float)(hw >> 10);
        const float u = fu[hw], v = fv[hw];
        const float du = u - (x * pf[0] + y * pf[1] + pf[2]);
        const float dv = v - (x * pf[3] + y * pf[4] + pf[5]);
        atomicAdd(&rbins[segc - 1], sqrtf(du * du + dv * dv));
    }
    __syncthreads();
    if (threadIdx.x < NSEG)
        atomicAdd(&res_sum[b * NSEG + threadIdx.x], (double)rbins[threadIdx.x]);
}

// ---------------- finalize: homog, sharp, smooth ----------------
__global__ __launch_bounds__(128) void final_kernel(
    const double* __restrict__ moments,
    const double* __restrict__ res_sum,
    const int*    __restrict__ valid,
    const double* __restrict__ scal,
    const unsigned* __restrict__ maxfg_bits,
    float* __restrict__ out)
{
    const int i = threadIdx.x;
    const double n = moments[i * 14];
    const int vh = valid[i];
    const double rm = vh ? res_sum[i] / (n > 1.0 ? n : 1.0) : 0.0;
    __shared__ double sr[128];
    __shared__ int sc[128];
    sr[i] = rm; sc[i] = vh;
    __syncthreads();
    for (int s = 64; s > 0; s >>= 1) {
        if (i < s) { sr[i] += sr[i + s]; sc[i] += sc[i + s]; }
        __syncthreads();
    }
    if (i == 0) {
        out[0] = (float)(sr[0] / (double)(sc[0] > 1 ? sc[0] : 1));
        const double sb = scal[2], sbf = scal[3];
        const double maxfg = (double)__uint_as_float(*maxfg_bits);
        const double maxb = (sb > 0.0) ? 1.0 : 0.0;
        out[1] = (float)((sb - sbf / (maxfg + 1e-6)) / (maxb + 1e-6) / (double)NPIX);
        const double smooth = scal[0] / (double)(2LL * BB * HH * (WW - 1)) +
                              scal[1] / (double)(2LL * BB * (HH - 1) * WW);
        out[3] = (float)smooth;
    }
}

extern "C" void kernel_launch(void* const* d_in, const int* in_sizes, int n_in,
                              void* d_out, int out_size, void* d_ws, size_t ws_size,
                              hipStream_t stream)
{
    const float* flow   = (const float*)d_in[0];
    const int*   masks  = (const int*)d_in[1];
    const float* images = (const float*)d_in[2];
    float* out = (float*)d_out;

    char* ws = (char*)d_ws;
    // layout: moments f64[1792] | res_sum f64[128] | scal f64[4] | maxfg u32 | params f32[768] | valid i32[128]
    double*   moments = (double*)(ws);             // 0     .. 14336
    double*   res_sum = (double*)(ws + 14336);     // 14336 .. 15360
    double*   scal    = (double*)(ws + 15360);     // 15360 .. 15392
    unsigned* maxfg   = (unsigned*)(ws + 15392);   // 15392 .. 15396
    float*    params  = (float*)(ws + 15396);      // 15396 .. 18468
    int*      valid   = (int*)(ws + 18468);        // 18468 .. 18980

    hipMemsetAsync(d_ws, 0, 19456, stream);

    pass1_kernel<<<dim3(NPIX / 4096), dim3(256), 0, stream>>>(
        flow, masks, images, moments, scal, maxfg);
    solve_kernel<<<dim3(1), dim3(128), 0, stream>>>(moments, params, valid, out);
    pass2_kernel<<<dim3(NPIX / 2048), dim3(256), 0, stream>>>(
        flow, masks, params, valid, res_sum);
    final_kernel<<<dim3(1), dim3(128), 0, stream>>>(
        moments, res_sum, valid, scal, maxfg, out);
}